// Round 3
// baseline (302.049 us; speedup 1.0000x reference)
//
#include <hip/hip_runtime.h>

// PrimalCosAttention fused kernel. R3: bf16 MFMA GEMMs (16x16x32), fp32 I/O.
// B=4 H=12 N=4096 D=64 E=32. One block = one (b,h) x 64-row n-tile, 4 waves.
// Wave w owns rows [16w,16w+16): GEMM1 -> S staging -> GEMM2 need no barriers
// beyond the single phase-1 __syncthreads (slabs are wave-private, weights RO).

namespace {
constexpr int Hh = 12;
constexpr int Nn = 4096;
constexpr int Dd = 64;
// output offsets in floats
constexpr int O_ATTN = 0;
constexpr int O_ES   = 12582912;
constexpr int O_RS   = 18874368;
constexpr int O_WE   = 25165824;
constexpr int O_WR   = 25190400;
constexpr int O_Q    = 25214976;
constexpr int O_K    = 37797888;
constexpr int O_LAM  = 50380800;
}

typedef float  v4f  __attribute__((ext_vector_type(4)));
typedef __bf16 v8bf __attribute__((ext_vector_type(8)));

// fp32 -> bf16 round-to-nearest-even (inputs are finite; no NaN handling)
__device__ __forceinline__ unsigned short f2b(float f) {
    unsigned int x = __float_as_uint(f);
    x += 0x7fffu + ((x >> 16) & 1u);
    return (unsigned short)(x >> 16);
}

// Swizzled index (in ushorts) into a [rows][64] bf16 matrix.
// 16B chunk index (k>>3) is XORed with (row&7) so MFMA fragment reads
// (16 lanes, same chunk, 16 rows) spread across banks: 2-way max (free).
__device__ __forceinline__ int swz(int row, int k) {
    return row * 64 + (((k >> 3) ^ (row & 7)) << 3) + (k & 7);
}

__global__ __launch_bounds__(256, 4)
void pca_fused(const float* __restrict__ Q, const float* __restrict__ Kp,
               const float* __restrict__ we, const float* __restrict__ wr,
               const float* __restrict__ mask, const float* __restrict__ W,
               const float* __restrict__ bias, const float* __restrict__ Lam,
               float* __restrict__ out)
{
    // 32 KiB total LDS (bf16 everywhere)
    __shared__ __align__(16) unsigned short Qs[4096];   // Qn [64][64]; reused as S
    __shared__ __align__(16) unsigned short Ks[4096];   // Kn [64][64]
    __shared__ __align__(16) unsigned short WEs[2048];  // we_h^T [e 32][d 64]
    __shared__ __align__(16) unsigned short WRs[2048];  // wr_h^T [e 32][d 64]
    __shared__ __align__(16) unsigned short Ws_[4096];  // W      [d 64][e 64]

    const int tid = threadIdx.x;
    const int bh  = blockIdx.x >> 6;        // b*12+h
    const int n0  = (blockIdx.x & 63) << 6;
    const int h   = bh % Hh;
    const int bb  = bh / Hh;

    // ---- passthrough outputs (we0 / wr0 / Lambda), float4, blocks 0..48 ----
    if (blockIdx.x < 49) {
        int i4 = blockIdx.x * 256 + tid;    // float4 index
        if (i4 < 6144) {
            ((float4*)(out + O_WE))[i4] = ((const float4*)we)[i4];
        } else if (i4 < 12288) {
            ((float4*)(out + O_WR))[i4 - 6144] = ((const float4*)wr)[i4 - 6144];
        } else if (i4 < 12384) {
            ((float4*)(out + O_LAM))[i4 - 12288] = ((const float4*)Lam)[i4 - 12288];
        }
    }

    // ---- stage weights to bf16 LDS ----
    {
        const float* weh = we + h * 2048;   // [d 64][e 32]
        const float* wrh = wr + h * 2048;
#pragma unroll
        for (int j = 0; j < 8; ++j) {
            int i = tid + 256 * j;          // 0..2047
            int d = i >> 5, e = i & 31;
            WEs[swz(e, d)] = f2b(weh[i]);   // transpose: row=e, k=d
            WRs[swz(e, d)] = f2b(wrh[i]);
        }
#pragma unroll
        for (int j = 0; j < 16; ++j) {
            int i = tid + 256 * j;          // 0..4095, W is [d 64][e2 64]
            int d = i >> 6, e = i & 63;
            Ws_[swz(d, e)] = f2b(W[i]);     // native: row=d, k=e
        }
    }

    // ---- load Q/K tile, L2-normalize, write q/k fp32 outs, stage bf16 ----
    {
        const int rr = tid >> 4;
        const int c4 = (tid & 15) << 2;
#pragma unroll
        for (int p = 0; p < 4; ++p) {
            int r = p * 16 + rr;
            int g = (bh * Nn + n0 + r) * Dd + c4;
            float4 q4 = *(const float4*)(Q + g);
            float4 k4 = *(const float4*)(Kp + g);
            float sq = q4.x*q4.x + q4.y*q4.y + q4.z*q4.z + q4.w*q4.w;
            float sk = k4.x*k4.x + k4.y*k4.y + k4.z*k4.z + k4.w*k4.w;
#pragma unroll
            for (int m = 1; m < 16; m <<= 1) {
                sq += __shfl_xor(sq, m, 64);
                sk += __shfl_xor(sk, m, 64);
            }
            float iq = 1.0f / fmaxf(sqrtf(sq), 1e-12f);
            float ik = 1.0f / fmaxf(sqrtf(sk), 1e-12f);
            q4.x *= iq; q4.y *= iq; q4.z *= iq; q4.w *= iq;
            k4.x *= ik; k4.y *= ik; k4.z *= ik; k4.w *= ik;
            *(float4*)(out + O_Q + g) = q4;
            *(float4*)(out + O_K + g) = k4;
            int a = swz(r, c4);             // c4&7 in {0,4}: 8B-aligned ushort4
            *(ushort4*)(Qs + a) = make_ushort4(f2b(q4.x), f2b(q4.y), f2b(q4.z), f2b(q4.w));
            *(ushort4*)(Ks + a) = make_ushort4(f2b(k4.x), f2b(k4.y), f2b(k4.z), f2b(k4.w));
        }
    }
    __syncthreads();   // the only barrier

    const int w    = tid >> 6;        // wave id, owns rows [16w, 16w+16)
    const int lane = tid & 63;
    const int quad = lane >> 4;
    const int n16  = lane & 15;
    const int m    = w * 16 + n16;    // A-operand row for this lane

    // fragment load: row-major swizzled [.][64] bf16, kb selects 32-wide K half
    auto ldf = [&](const unsigned short* b, int row, int kb) -> v8bf {
        return *(const v8bf*)(b + row * 64 + ((((kb << 2) + quad) ^ (row & 7)) << 3));
    };

    // ---- GEMM1: escore = Qn @ we_h, rscore = Kn @ wr_h ----
    v8bf aq0 = ldf(Qs, m, 0), aq1 = ldf(Qs, m, 1);
    v8bf ak0 = ldf(Ks, m, 0), ak1 = ldf(Ks, m, 1);
    v4f accE[2], accR[2];
#pragma unroll
    for (int nt = 0; nt < 2; ++nt) {
        int er = nt * 16 + n16;
        accE[nt] = (v4f){0.f, 0.f, 0.f, 0.f};
        accR[nt] = (v4f){0.f, 0.f, 0.f, 0.f};
        accE[nt] = __builtin_amdgcn_mfma_f32_16x16x32_bf16(aq0, ldf(WEs, er, 0), accE[nt], 0, 0, 0);
        accE[nt] = __builtin_amdgcn_mfma_f32_16x16x32_bf16(aq1, ldf(WEs, er, 1), accE[nt], 0, 0, 0);
        accR[nt] = __builtin_amdgcn_mfma_f32_16x16x32_bf16(ak0, ldf(WRs, er, 0), accR[nt], 0, 0, 0);
        accR[nt] = __builtin_amdgcn_mfma_f32_16x16x32_bf16(ak1, ldf(WRs, er, 1), accR[nt], 0, 0, 0);
    }

    // ---- write escore/rscore fp32; stage S=[escore|rscore] bf16 into Qs ----
    // C-layout: col = lane&15, row = quad*4 + i  (within this wave's 16-row slab)
#pragma unroll
    for (int nt = 0; nt < 2; ++nt) {
#pragma unroll
        for (int i = 0; i < 4; ++i) {
            int r = w * 16 + quad * 4 + i;           // row in 64-tile (wave-private)
            int n = n0 + r;
            out[O_ES + (bh * Nn + n) * 32 + nt * 16 + n16] = accE[nt][i];
            out[O_RS + (bh * Nn + n) * 32 + nt * 16 + n16] = accR[nt][i];
            Qs[swz(r, nt * 16 + n16)]      = f2b(accE[nt][i]);
            Qs[swz(r, 32 + nt * 16 + n16)] = f2b(accR[nt][i]);
        }
    }

    // ---- GEMM2: attn = S @ W^T + b, then * mask (no barrier: slab-private) ----
    v8bf as0 = ldf(Qs, m, 0), as1 = ldf(Qs, m, 1);
    v4f accD[4];
#pragma unroll
    for (int nt = 0; nt < 4; ++nt) {
        float bv = bias[nt * 16 + n16];
        accD[nt] = (v4f){bv, bv, bv, bv};
        accD[nt] = __builtin_amdgcn_mfma_f32_16x16x32_bf16(as0, ldf(Ws_, nt * 16 + n16, 0), accD[nt], 0, 0, 0);
        accD[nt] = __builtin_amdgcn_mfma_f32_16x16x32_bf16(as1, ldf(Ws_, nt * 16 + n16, 1), accD[nt], 0, 0, 0);
    }
    float mv[4];
#pragma unroll
    for (int i = 0; i < 4; ++i) mv[i] = mask[bb * Nn + n0 + w * 16 + quad * 4 + i];
#pragma unroll
    for (int nt = 0; nt < 4; ++nt) {
#pragma unroll
        for (int i = 0; i < 4; ++i) {
            int n = n0 + w * 16 + quad * 4 + i;
            out[O_ATTN + (bh * Nn + n) * 64 + nt * 16 + n16] = accD[nt][i] * mv[i];
        }
    }
}

extern "C" void kernel_launch(void* const* d_in, const int* in_sizes, int n_in,
                              void* d_out, int out_size, void* d_ws, size_t ws_size,
                              hipStream_t stream) {
    const float* Q    = (const float*)d_in[0];
    const float* Kp   = (const float*)d_in[1];
    const float* we   = (const float*)d_in[2];
    const float* wr   = (const float*)d_in[3];
    const float* mask = (const float*)d_in[4];
    const float* W    = (const float*)d_in[5];
    const float* bias = (const float*)d_in[6];
    const float* Lam  = (const float*)d_in[7];
    float* out = (float*)d_out;

    pca_fused<<<dim3(48 * 64), dim3(256), 0, stream>>>(Q, Kp, we, wr, mask, W, bias, Lam, out);
}